// Round 1
// baseline (317.827 us; speedup 1.0000x reference)
//
#include <hip/hip_runtime.h>

#define B 64
#define P 16320
#define NOBJ 32
#define NC 21
#define BPTOT (B * P)

constexpr int BLK = 256;
constexpr int PBLKS = (P + BLK - 1) / BLK;  // 64

__device__ __forceinline__ unsigned long long packKey(float v, int p) {
    unsigned int bits = __float_as_uint(v);
    unsigned int key = bits ^ ((bits & 0x80000000u) ? 0xFFFFFFFFu : 0x80000000u);
    return ((unsigned long long)key << 32) | (unsigned int)(~(unsigned int)p);
}

// ---------------- init: zero accumulators, init per-truth best-prior packs ----
__global__ void k_init(unsigned long long* bp_packed, int* num_pos, float* ll_b, float* lc_b) {
    int t = threadIdx.x;
    // pack(-1.0f, idx 0): key(-1.0)=0x407FFFFF, ~0 = 0xFFFFFFFF
    for (int i = t; i < B * NOBJ; i += BLK) bp_packed[i] = 0x407FFFFFFFFFFFFFULL;
    if (t < B) { num_pos[t] = 0; ll_b[t] = 0.f; lc_b[t] = 0.f; }
}

// ---------------- phase 1: decode, IoU, per-prior & per-truth argmax ---------
__global__ __launch_bounds__(BLK) void k_phase1(
    const float* __restrict__ arm_loc, const float* __restrict__ arm_conf,
    const float* __restrict__ priors, const float* __restrict__ truths,
    float* __restrict__ bt_val, int* __restrict__ bt_idx,
    unsigned long long* __restrict__ bp_packed)
{
    int b = blockIdx.y;
    int p = blockIdx.x * BLK + threadIdx.x;
    __shared__ float tr[NOBJ * 4];
    __shared__ unsigned long long blk_best[NOBJ];
    if (threadIdx.x < NOBJ * 4) tr[threadIdx.x] = truths[b * NOBJ * 4 + threadIdx.x];
    if (threadIdx.x < NOBJ) blk_best[threadIdx.x] = 0ULL;
    __syncthreads();

    bool active = p < P;
    bool reserve = false;
    float x1 = 0.f, y1 = 0.f, x2 = 0.f, y2 = 0.f;
    if (active) {
        size_t bpi = (size_t)b * P + p;
        float c0 = arm_conf[bpi * 2 + 0];
        float c1 = arm_conf[bpi * 2 + 1];
        float mc = fmaxf(c0, c1);
        float e0 = expf(c0 - mc), e1 = expf(c1 - mc);
        reserve = (e1 / (e0 + e1)) > 0.01f;
        const float* lp = arm_loc + bpi * 4;
        float l0 = lp[0], l1 = lp[1], l2 = lp[2], l3 = lp[3];
        float pcx = priors[p * 4 + 0], pcy = priors[p * 4 + 1];
        float pw = priors[p * 4 + 2], ph = priors[p * 4 + 3];
        float dcx = pcx + l0 * 0.1f * pw;
        float dcy = pcy + l1 * 0.1f * ph;
        float dw = pw * expf(l2 * 0.2f);
        float dh = ph * expf(l3 * 0.2f);
        x1 = dcx - dw * 0.5f; y1 = dcy - dh * 0.5f;
        x2 = dcx + dw * 0.5f; y2 = dcy + dh * 0.5f;
    }
    float areaP = (x2 - x1) * (y2 - y1);
    float bestv = -1.0f; int besti = 0;

    for (int j = 0; j < NOBJ; j++) {
        unsigned long long pk = 0ULL;
        if (reserve) {
            float tx1 = tr[j * 4 + 0], ty1 = tr[j * 4 + 1];
            float tx2 = tr[j * 4 + 2], ty2 = tr[j * 4 + 3];
            float iw = fmaxf(fminf(x2, tx2) - fmaxf(x1, tx1), 0.f);
            float ih = fmaxf(fminf(y2, ty2) - fmaxf(y1, ty1), 0.f);
            float inter = iw * ih;
            float areaT = (tx2 - tx1) * (ty2 - ty1);
            float iou = inter / (areaT + areaP - inter);
            if (iou > bestv) { bestv = iou; besti = j; }  // first-max tie-break
            pk = packKey(iou, p);
        }
        // wave butterfly max (64 lanes)
        #pragma unroll
        for (int off = 32; off; off >>= 1) {
            unsigned long long o = __shfl_xor(pk, off, 64);
            if (o > pk) pk = o;
        }
        if ((threadIdx.x & 63) == 0 && pk) atomicMax(&blk_best[j], pk);
    }

    if (active) {
        size_t bpi = (size_t)b * P + p;
        bt_val[bpi] = reserve ? bestv : -1.0f;
        bt_idx[bpi] = besti;
    }
    __syncthreads();
    if (threadIdx.x < NOBJ) {
        unsigned long long v = blk_best[threadIdx.x];
        if (v) atomicMax(&bp_packed[b * NOBJ + threadIdx.x], v);
    }
}

// ---------------- force-match override (last-write-wins, sequential per batch)
__global__ void k_override(const unsigned long long* __restrict__ bp_packed,
                           float* __restrict__ bt_val, int* __restrict__ bt_idx) {
    int b = threadIdx.x;
    if (b >= B) return;
    for (int j = 0; j < NOBJ; j++) {
        unsigned long long pk = bp_packed[b * NOBJ + j];
        unsigned int pi = ~(unsigned int)(pk & 0xFFFFFFFFULL);
        bt_val[(size_t)b * P + pi] = 2.0f;
        bt_idx[(size_t)b * P + pi] = j;
    }
}

// ---------------- phase 2: conf targets, CE, smooth-L1, mine array -----------
__global__ __launch_bounds__(BLK) void k_phase2(
    const float* __restrict__ arm_loc, const float* __restrict__ arm_conf,
    const float* __restrict__ odm_loc, const float* __restrict__ odm_conf,
    const float* __restrict__ priors, const float* __restrict__ truths,
    const int* __restrict__ labels,
    const float* __restrict__ bt_val, const int* __restrict__ bt_idx,
    float* __restrict__ mine, int* __restrict__ num_pos,
    float* __restrict__ ll_b, float* __restrict__ lc_b)
{
    int b = blockIdx.y;
    int p = blockIdx.x * BLK + threadIdx.x;
    bool active = p < P;
    float ll = 0.f, lc = 0.f; int np = 0;

    if (active) {
        size_t bpi = (size_t)b * P + p;
        float c0 = arm_conf[bpi * 2 + 0];
        float c1 = arm_conf[bpi * 2 + 1];
        float mc = fmaxf(c0, c1);
        float e0 = expf(c0 - mc), e1 = expf(c1 - mc);
        bool reserve = (e1 / (e0 + e1)) > 0.01f;

        float bv = bt_val[bpi];
        int bi = bt_idx[bpi];
        int conf;
        if (!reserve) conf = -1;
        else if (bv < 0.5f) conf = 0;
        else conf = labels[b * NOBJ + bi] + 1;

        const float* oc = odm_conf + bpi * NC;
        float m = oc[0];
        #pragma unroll
        for (int k = 1; k < NC; k++) m = fmaxf(m, oc[k]);
        float s = 0.f;
        #pragma unroll
        for (int k = 0; k < NC; k++) s += expf(oc[k] - m);
        int t0 = conf > 0 ? conf : 0;
        float ce = m + logf(s) - oc[t0];

        bool pos = conf > 0;
        mine[bpi] = (pos || conf == -1) ? 0.f : ce;

        if (pos) {
            np = 1; lc = ce;
            const float* lp = arm_loc + bpi * 4;
            float pcx = priors[p * 4 + 0], pcy = priors[p * 4 + 1];
            float pw = priors[p * 4 + 2], ph = priors[p * 4 + 3];
            float dcx = pcx + lp[0] * 0.1f * pw;
            float dcy = pcy + lp[1] * 0.1f * ph;
            float dw = pw * expf(lp[2] * 0.2f);
            float dh = ph * expf(lp[3] * 0.2f);
            float rx1 = dcx - dw * 0.5f, ry1 = dcy - dh * 0.5f;
            float rx2 = dcx + dw * 0.5f, ry2 = dcy + dh * 0.5f;
            float rcx = (rx1 + rx2) * 0.5f, rcy = (ry1 + ry2) * 0.5f;
            float rw = rx2 - rx1, rh = ry2 - ry1;
            const float* tb = truths + ((size_t)b * NOBJ + bi) * 4;
            float g0 = ((tb[0] + tb[2]) * 0.5f - rcx) / (0.1f * rw);
            float g1 = ((tb[1] + tb[3]) * 0.5f - rcy) / (0.1f * rh);
            float g2 = logf((tb[2] - tb[0]) / rw) / 0.2f;
            float g3 = logf((tb[3] - tb[1]) / rh) / 0.2f;
            float g[4] = {g0, g1, g2, g3};
            const float* ol = odm_loc + bpi * 4;
            #pragma unroll
            for (int k = 0; k < 4; k++) {
                float d = fabsf(ol[k] - g[k]);
                ll += (d < 1.f) ? 0.5f * d * d : d - 0.5f;
            }
        }
    }

    // block reduce -> per-batch atomics
    #pragma unroll
    for (int off = 32; off; off >>= 1) {
        ll += __shfl_xor(ll, off, 64);
        lc += __shfl_xor(lc, off, 64);
        np += __shfl_xor(np, off, 64);
    }
    __shared__ float sll[BLK / 64], slc[BLK / 64];
    __shared__ int snp[BLK / 64];
    int wid = threadIdx.x >> 6, lane = threadIdx.x & 63;
    if (lane == 0) { sll[wid] = ll; slc[wid] = lc; snp[wid] = np; }
    __syncthreads();
    if (threadIdx.x == 0) {
        float a = 0.f, c = 0.f; int n = 0;
        for (int w = 0; w < BLK / 64; w++) { a += sll[w]; c += slc[w]; n += snp[w]; }
        if (a != 0.f) atomicAdd(&ll_b[b], a);
        if (c != 0.f) atomicAdd(&lc_b[b], c);
        if (n) atomicAdd(&num_pos[b], n);
    }
}

// ---------------- per-batch top-K CE sum via 8-bit radix select --------------
__global__ __launch_bounds__(BLK) void k_select(
    const float* __restrict__ mine, const int* __restrict__ num_pos,
    float* __restrict__ lc_b)
{
    int b = blockIdx.x;
    int K0 = num_pos[b] * 3;
    if (K0 > P - 1) K0 = P - 1;
    if (K0 <= 0) return;
    const float* row = mine + (size_t)b * P;

    __shared__ unsigned int hist[256];
    __shared__ unsigned int sfx[256];
    __shared__ unsigned int s_beta, s_K;

    unsigned int K = (unsigned int)K0;
    unsigned int prefix = 0, maskDone = 0;

    for (int pass = 0; pass < 4; pass++) {
        int shift = 24 - pass * 8;
        hist[threadIdx.x] = 0;
        __syncthreads();
        for (int i = threadIdx.x; i < P; i += BLK) {
            unsigned int bits = __float_as_uint(row[i]);
            if ((bits & maskDone) == prefix) atomicAdd(&hist[(bits >> shift) & 255u], 1u);
        }
        __syncthreads();
        // inclusive suffix sum (Hillis-Steele)
        sfx[threadIdx.x] = hist[threadIdx.x];
        __syncthreads();
        for (int off = 1; off < 256; off <<= 1) {
            unsigned int add = (threadIdx.x + off < 256) ? sfx[threadIdx.x + off] : 0u;
            __syncthreads();
            sfx[threadIdx.x] += add;
            __syncthreads();
        }
        unsigned int Sn = (threadIdx.x < 255) ? sfx[threadIdx.x + 1] : 0u;
        if (sfx[threadIdx.x] >= K && Sn < K) { s_beta = threadIdx.x; s_K = K - Sn; }
        __syncthreads();
        prefix |= (s_beta << shift);
        maskDone |= (0xFFu << shift);
        K = s_K;
        __syncthreads();
    }

    unsigned int tBits = prefix;
    float t = __uint_as_float(tBits);

    unsigned int mcnt = 0; float ssum = 0.f;
    for (int i = threadIdx.x; i < P; i += BLK) {
        float v = row[i];
        if (__float_as_uint(v) > tBits) { mcnt++; ssum += v; }
    }
    #pragma unroll
    for (int off = 32; off; off >>= 1) {
        mcnt += __shfl_xor(mcnt, off, 64);
        ssum += __shfl_xor(ssum, off, 64);
    }
    __shared__ float sS[BLK / 64];
    __shared__ unsigned int sM[BLK / 64];
    int wid = threadIdx.x >> 6, lane = threadIdx.x & 63;
    if (lane == 0) { sS[wid] = ssum; sM[wid] = mcnt; }
    __syncthreads();
    if (threadIdx.x == 0) {
        float S = 0.f; unsigned int M = 0;
        for (int w = 0; w < BLK / 64; w++) { S += sS[w]; M += sM[w]; }
        float contrib = S + (float)(K0 - (int)M) * t;
        atomicAdd(&lc_b[b], contrib);
    }
}

// ---------------- finalize ---------------------------------------------------
__global__ void k_final(const int* __restrict__ num_pos, const float* __restrict__ ll_b,
                        const float* __restrict__ lc_b, float* __restrict__ out) {
    int t = threadIdx.x;  // 64 threads
    int np = num_pos[t];
    float ll = ll_b[t];
    float lc = lc_b[t];
    #pragma unroll
    for (int off = 32; off; off >>= 1) {
        np += __shfl_xor(np, off, 64);
        ll += __shfl_xor(ll, off, 64);
        lc += __shfl_xor(lc, off, 64);
    }
    if (t == 0) {
        float tn = (float)np;
        out[0] = ll / tn;
        out[1] = lc / tn;
    }
}

extern "C" void kernel_launch(void* const* d_in, const int* in_sizes, int n_in,
                              void* d_out, int out_size, void* d_ws, size_t ws_size,
                              hipStream_t stream) {
    const float* arm_loc  = (const float*)d_in[0];
    const float* arm_conf = (const float*)d_in[1];
    const float* odm_loc  = (const float*)d_in[2];
    const float* odm_conf = (const float*)d_in[3];
    const float* priors   = (const float*)d_in[4];
    const float* truths   = (const float*)d_in[5];
    const int*   labels   = (const int*)d_in[6];
    float* out = (float*)d_out;

    char* ws = (char*)d_ws;
    float* bt_val = (float*)ws;                               // BPTOT f32
    int*   bt_idx = (int*)(ws + 4ull * BPTOT);                // BPTOT i32
    float* mine   = (float*)(ws + 8ull * BPTOT);              // BPTOT f32
    unsigned long long* bp_packed = (unsigned long long*)(ws + 12ull * BPTOT);  // B*NOBJ u64
    int*   num_pos = (int*)(ws + 12ull * BPTOT + 8ull * B * NOBJ);
    float* ll_b    = (float*)(ws + 12ull * BPTOT + 8ull * B * NOBJ + 4ull * B);
    float* lc_b    = (float*)(ws + 12ull * BPTOT + 8ull * B * NOBJ + 8ull * B);

    dim3 grid(PBLKS, B);

    k_init<<<1, BLK, 0, stream>>>(bp_packed, num_pos, ll_b, lc_b);
    k_phase1<<<grid, BLK, 0, stream>>>(arm_loc, arm_conf, priors, truths,
                                       bt_val, bt_idx, bp_packed);
    k_override<<<1, 64, 0, stream>>>(bp_packed, bt_val, bt_idx);
    k_phase2<<<grid, BLK, 0, stream>>>(arm_loc, arm_conf, odm_loc, odm_conf,
                                       priors, truths, labels, bt_val, bt_idx,
                                       mine, num_pos, ll_b, lc_b);
    k_select<<<B, BLK, 0, stream>>>(mine, num_pos, lc_b);
    k_final<<<1, 64, 0, stream>>>(num_pos, ll_b, lc_b, out);
}

// Round 2
// 262.301 us; speedup vs baseline: 1.2117x; 1.2117x over previous
//
#include <hip/hip_runtime.h>

#define B 64
#define P 16320
#define NOBJ 32
#define NC 21

constexpr int T1 = 512;
constexpr int G1 = 4;
constexpr int C1 = T1 * G1;               // 2048 priors per block
constexpr int NP1 = (P + C1 - 1) / C1;    // 8
constexpr int BLK2 = 256;
constexpr int PBLK2 = (P + BLK2 - 1) / BLK2;  // 64
constexpr int TSEL = 1024;
__device__ constexpr float LN99 = 4.59511985013459f;  // ln(99): softmax(c1)>0.01 <=> c0-c1 < ln99

// ---------------- init: accumulators + per-truth best-prior packs ------------
__global__ void k_init(unsigned long long* bp_packed, int* num_pos, float* ll_b, float* lc_b) {
    int t = threadIdx.x;
    // pack(-1.0f, idx 0): key(-1.0)=0x407FFFFF, ~0 = 0xFFFFFFFF
    for (int i = t; i < B * NOBJ; i += 256) bp_packed[i] = 0x407FFFFFFFFFFFFFULL;
    if (t < B) { num_pos[t] = 0; ll_b[t] = 0.f; lc_b[t] = 0.f; }
}

// ---------------- phase 1: decode, IoU, per-prior & per-truth argmax ---------
// Each thread owns G1=4 priors; per-truth running max kept in registers
// (f32 val[32] + 2-bit g-selector), one wave butterfly per 2048 priors.
__global__ __launch_bounds__(T1) void k_phase1(
    const float* __restrict__ arm_loc, const float* __restrict__ arm_conf,
    const float* __restrict__ priors, const float* __restrict__ truths,
    int* __restrict__ bt_pack, unsigned long long* __restrict__ bp_packed)
{
    int b = blockIdx.y;
    int base = blockIdx.x * C1;
    int tid = threadIdx.x;
    __shared__ float4 tr4[NOBJ];
    __shared__ float tarea[NOBJ];
    __shared__ unsigned long long blk_best[NOBJ];
    if (tid < NOBJ) {
        float4 t = ((const float4*)truths)[b * NOBJ + tid];
        tr4[tid] = t;
        tarea[tid] = (t.z - t.x) * (t.w - t.y);
        blk_best[tid] = 0ULL;
    }
    __syncthreads();

    float x1[G1], y1[G1], x2[G1], y2[G1], areaP[G1];
    bool resv[G1], act[G1];
    float bestv[G1]; int bestj[G1];
    #pragma unroll
    for (int g = 0; g < G1; g++) {
        int p = base + g * T1 + tid;
        act[g] = p < P;
        resv[g] = false;
        x1[g] = y1[g] = x2[g] = y2[g] = 0.f; areaP[g] = 0.f;
        bestv[g] = -1.f; bestj[g] = 0;
        if (act[g]) {
            size_t bpi = (size_t)b * P + p;
            float2 cc = ((const float2*)arm_conf)[bpi];
            resv[g] = (cc.x - cc.y) < LN99;
            float4 l = ((const float4*)arm_loc)[bpi];
            float4 pr = ((const float4*)priors)[p];
            float dcx = pr.x + l.x * 0.1f * pr.z;
            float dcy = pr.y + l.y * 0.1f * pr.w;
            float dw = pr.z * __expf(l.z * 0.2f);
            float dh = pr.w * __expf(l.w * 0.2f);
            x1[g] = dcx - dw * 0.5f; y1[g] = dcy - dh * 0.5f;
            x2[g] = dcx + dw * 0.5f; y2[g] = dcy + dh * 0.5f;
            areaP[g] = (x2[g] - x1[g]) * (y2[g] - y1[g]);
        }
    }

    float val[NOBJ];
    unsigned gsel[2] = {0u, 0u};
    #pragma unroll
    for (int j = 0; j < NOBJ; j++) val[j] = -1.f;

    #pragma unroll
    for (int j = 0; j < NOBJ; j++) {
        float4 t = tr4[j];
        float ta = tarea[j];
        #pragma unroll
        for (int g = 0; g < G1; g++) {
            float iw = fmaxf(fminf(x2[g], t.z) - fmaxf(x1[g], t.x), 0.f);
            float ih = fmaxf(fminf(y2[g], t.w) - fmaxf(y1[g], t.y), 0.f);
            float inter = iw * ih;
            float iou = inter * __builtin_amdgcn_rcpf(ta + areaP[g] - inter);
            if (resv[g] && iou > bestv[g]) { bestv[g] = iou; bestj[g] = j; }
            if (resv[g] && iou > val[j]) {
                val[j] = iou;
                gsel[j >> 4] = (gsel[j >> 4] & ~(3u << (2 * (j & 15))))
                             | ((unsigned)g << (2 * (j & 15)));
            }
        }
    }

    // per-prior result: (bestj << 1) | (overlap >= 0.5); non-reserve -> 0 (conf=-1 anyway)
    #pragma unroll
    for (int g = 0; g < G1; g++) {
        if (act[g]) {
            int p = base + g * T1 + tid;
            int ge = (resv[g] && !(bestv[g] < 0.5f)) ? 1 : 0;
            bt_pack[(size_t)b * P + p] = (bestj[g] << 1) | ge;
        }
    }

    // per-truth reduction: wave butterfly on packed (valbits | sign, ~p)
    #pragma unroll
    for (int j = 0; j < NOBJ; j++) {
        unsigned g = (gsel[j >> 4] >> (2 * (j & 15))) & 3u;
        unsigned p = (unsigned)(base + (int)g * T1 + tid);
        unsigned long long pk = (val[j] >= 0.f)
            ? (((unsigned long long)(__float_as_uint(val[j]) | 0x80000000u) << 32)
               | (unsigned)~p)
            : 0ULL;
        #pragma unroll
        for (int off = 32; off; off >>= 1) {
            unsigned long long o = __shfl_xor(pk, off, 64);
            pk = o > pk ? o : pk;
        }
        if ((tid & 63) == 0 && pk) atomicMax(&blk_best[j], pk);
    }
    __syncthreads();
    if (tid < NOBJ && blk_best[tid]) atomicMax(&bp_packed[b * NOBJ + tid], blk_best[tid]);
}

// ---------------- phase 2: override fold, conf/CE, smooth-L1, mine -----------
__global__ __launch_bounds__(BLK2) void k_phase2(
    const float* __restrict__ arm_loc, const float* __restrict__ arm_conf,
    const float* __restrict__ odm_loc, const float* __restrict__ odm_conf,
    const float* __restrict__ priors, const float* __restrict__ truths,
    const int* __restrict__ labels, const int* __restrict__ bt_pack,
    const unsigned long long* __restrict__ bp_packed,
    float* __restrict__ mine, int* __restrict__ num_pos,
    float* __restrict__ ll_b, float* __restrict__ lc_b)
{
    int b = blockIdx.y;
    int p = blockIdx.x * BLK2 + threadIdx.x;
    __shared__ unsigned s_pi[NOBJ];
    __shared__ int s_lab[NOBJ];
    if (threadIdx.x < NOBJ) {
        s_pi[threadIdx.x] = ~(unsigned)(bp_packed[b * NOBJ + threadIdx.x] & 0xFFFFFFFFULL);
        s_lab[threadIdx.x] = labels[b * NOBJ + threadIdx.x];
    }
    __syncthreads();

    float ll = 0.f, lc = 0.f; int np = 0;
    if (p < P) {
        size_t bpi = (size_t)b * P + p;
        float2 cc = ((const float2*)arm_conf)[bpi];
        bool reserve = (cc.x - cc.y) < LN99;

        int pk = bt_pack[bpi];
        int bi = pk >> 1;
        int ge = pk & 1;
        // force-match override; ascending j = last-write-wins (matches JAX scatter)
        #pragma unroll
        for (int j = 0; j < NOBJ; j++)
            if (s_pi[j] == (unsigned)p) { ge = 1; bi = j; }

        int conf = !reserve ? -1 : (ge ? s_lab[bi] + 1 : 0);

        const float* oc = odm_conf + bpi * NC;
        float vals[NC];
        #pragma unroll
        for (int k = 0; k < NC; k++) vals[k] = oc[k];
        float m = vals[0];
        #pragma unroll
        for (int k = 1; k < NC; k++) m = fmaxf(m, vals[k]);
        float s = 0.f;
        #pragma unroll
        for (int k = 0; k < NC; k++) s += __expf(vals[k] - m);
        int t0 = conf > 0 ? conf : 0;
        float ce = m + __logf(s) - oc[t0];   // reload: L1-hot, avoids scratch

        bool pos = conf > 0;
        mine[bpi] = (pos || conf == -1) ? 0.f : ce;

        if (pos) {
            np = 1; lc = ce;
            float4 l = ((const float4*)arm_loc)[bpi];
            float4 pr = ((const float4*)priors)[p];
            float dcx = pr.x + l.x * 0.1f * pr.z;
            float dcy = pr.y + l.y * 0.1f * pr.w;
            float dw = pr.z * __expf(l.z * 0.2f);
            float dh = pr.w * __expf(l.w * 0.2f);
            float rx1 = dcx - dw * 0.5f, ry1 = dcy - dh * 0.5f;
            float rx2 = dcx + dw * 0.5f, ry2 = dcy + dh * 0.5f;
            float rcx = (rx1 + rx2) * 0.5f, rcy = (ry1 + ry2) * 0.5f;
            float rw = rx2 - rx1, rh = ry2 - ry1;
            float4 tb = ((const float4*)truths)[b * NOBJ + bi];
            float g0 = ((tb.x + tb.z) * 0.5f - rcx) * __builtin_amdgcn_rcpf(0.1f * rw);
            float g1 = ((tb.y + tb.w) * 0.5f - rcy) * __builtin_amdgcn_rcpf(0.1f * rh);
            float g2 = __logf((tb.z - tb.x) * __builtin_amdgcn_rcpf(rw)) * 5.0f;
            float g3 = __logf((tb.w - tb.y) * __builtin_amdgcn_rcpf(rh)) * 5.0f;
            float4 ol = ((const float4*)odm_loc)[bpi];
            float gt[4] = {g0, g1, g2, g3};
            float od[4] = {ol.x, ol.y, ol.z, ol.w};
            #pragma unroll
            for (int k = 0; k < 4; k++) {
                float d = fabsf(od[k] - gt[k]);
                ll += (d < 1.f) ? 0.5f * d * d : d - 0.5f;
            }
        }
    }

    #pragma unroll
    for (int off = 32; off; off >>= 1) {
        ll += __shfl_xor(ll, off, 64);
        lc += __shfl_xor(lc, off, 64);
        np += __shfl_xor(np, off, 64);
    }
    __shared__ float sll[BLK2 / 64], slc[BLK2 / 64];
    __shared__ int snp[BLK2 / 64];
    int wid = threadIdx.x >> 6, lane = threadIdx.x & 63;
    if (lane == 0) { sll[wid] = ll; slc[wid] = lc; snp[wid] = np; }
    __syncthreads();
    if (threadIdx.x == 0) {
        float a = 0.f, c = 0.f; int n = 0;
        for (int w = 0; w < BLK2 / 64; w++) { a += sll[w]; c += slc[w]; n += snp[w]; }
        if (a != 0.f) atomicAdd(&ll_b[b], a);
        if (c != 0.f) atomicAdd(&lc_b[b], c);
        if (n) atomicAdd(&num_pos[b], n);
    }
}

// ---------------- per-batch top-K CE sum via 8-bit radix select --------------
__global__ __launch_bounds__(TSEL) void k_select(
    const float* __restrict__ mine, const int* __restrict__ num_pos,
    float* __restrict__ lc_b)
{
    int b = blockIdx.x;
    int tid = threadIdx.x;
    int K0 = num_pos[b] * 3;
    if (K0 > P - 1) K0 = P - 1;
    if (K0 <= 0) return;
    const float* row = mine + (size_t)b * P;

    __shared__ unsigned hist[256];
    __shared__ unsigned sfx[256];
    __shared__ unsigned s_beta, s_K;

    unsigned K = (unsigned)K0;
    unsigned prefix = 0, maskDone = 0;

    for (int pass = 0; pass < 4; pass++) {
        int shift = 24 - pass * 8;
        if (tid < 256) hist[tid] = 0;
        __syncthreads();
        for (int i = tid; i < P; i += TSEL) {
            unsigned bits = __float_as_uint(row[i]);
            if ((bits & maskDone) == prefix) atomicAdd(&hist[(bits >> shift) & 255u], 1u);
        }
        __syncthreads();
        if (tid < 256) sfx[tid] = hist[tid];
        __syncthreads();
        for (int off = 1; off < 256; off <<= 1) {
            unsigned add = 0;
            if (tid < 256 && tid + off < 256) add = sfx[tid + off];
            __syncthreads();
            if (tid < 256) sfx[tid] += add;
            __syncthreads();
        }
        if (tid < 256) {
            unsigned Sc = sfx[tid];
            unsigned Sn = (tid < 255) ? sfx[tid + 1] : 0u;
            if (Sc >= K && Sn < K) { s_beta = (unsigned)tid; s_K = K - Sn; }
        }
        __syncthreads();
        prefix |= (s_beta << shift);
        maskDone |= (0xFFu << shift);
        K = s_K;
        __syncthreads();
    }

    unsigned tBits = prefix;
    float t = __uint_as_float(tBits);

    unsigned mcnt = 0; float ssum = 0.f;
    for (int i = tid; i < P; i += TSEL) {
        float v = row[i];
        if (__float_as_uint(v) > tBits) { mcnt++; ssum += v; }
    }
    #pragma unroll
    for (int off = 32; off; off >>= 1) {
        mcnt += __shfl_xor(mcnt, off, 64);
        ssum += __shfl_xor(ssum, off, 64);
    }
    __shared__ float sS[TSEL / 64];
    __shared__ unsigned sM[TSEL / 64];
    int wid = tid >> 6, lane = tid & 63;
    if (lane == 0) { sS[wid] = ssum; sM[wid] = mcnt; }
    __syncthreads();
    if (tid == 0) {
        float S = 0.f; unsigned M = 0;
        for (int w = 0; w < TSEL / 64; w++) { S += sS[w]; M += sM[w]; }
        float contrib = S + (float)(K0 - (int)M) * t;
        atomicAdd(&lc_b[b], contrib);
    }
}

// ---------------- finalize ---------------------------------------------------
__global__ void k_final(const int* __restrict__ num_pos, const float* __restrict__ ll_b,
                        const float* __restrict__ lc_b, float* __restrict__ out) {
    int t = threadIdx.x;  // 64 threads
    int np = num_pos[t];
    float ll = ll_b[t];
    float lc = lc_b[t];
    #pragma unroll
    for (int off = 32; off; off >>= 1) {
        np += __shfl_xor(np, off, 64);
        ll += __shfl_xor(ll, off, 64);
        lc += __shfl_xor(lc, off, 64);
    }
    if (t == 0) {
        float tn = (float)np;
        out[0] = ll / tn;
        out[1] = lc / tn;
    }
}

extern "C" void kernel_launch(void* const* d_in, const int* in_sizes, int n_in,
                              void* d_out, int out_size, void* d_ws, size_t ws_size,
                              hipStream_t stream) {
    const float* arm_loc  = (const float*)d_in[0];
    const float* arm_conf = (const float*)d_in[1];
    const float* odm_loc  = (const float*)d_in[2];
    const float* odm_conf = (const float*)d_in[3];
    const float* priors   = (const float*)d_in[4];
    const float* truths   = (const float*)d_in[5];
    const int*   labels   = (const int*)d_in[6];
    float* out = (float*)d_out;

    char* ws = (char*)d_ws;
    const size_t BPTOT = (size_t)B * P;
    int*   bt_pack = (int*)ws;                                  // BPTOT i32
    float* mine    = (float*)(ws + 4ull * BPTOT);               // BPTOT f32
    unsigned long long* bp_packed = (unsigned long long*)(ws + 8ull * BPTOT);  // B*NOBJ u64
    int*   num_pos = (int*)(ws + 8ull * BPTOT + 8ull * B * NOBJ);
    float* ll_b    = (float*)(ws + 8ull * BPTOT + 8ull * B * NOBJ + 4ull * B);
    float* lc_b    = (float*)(ws + 8ull * BPTOT + 8ull * B * NOBJ + 8ull * B);

    k_init<<<1, 256, 0, stream>>>(bp_packed, num_pos, ll_b, lc_b);
    k_phase1<<<dim3(NP1, B), T1, 0, stream>>>(arm_loc, arm_conf, priors, truths,
                                              bt_pack, bp_packed);
    k_phase2<<<dim3(PBLK2, B), BLK2, 0, stream>>>(arm_loc, arm_conf, odm_loc, odm_conf,
                                                  priors, truths, labels, bt_pack,
                                                  bp_packed, mine, num_pos, ll_b, lc_b);
    k_select<<<B, TSEL, 0, stream>>>(mine, num_pos, lc_b);
    k_final<<<1, 64, 0, stream>>>(num_pos, ll_b, lc_b, out);
}